// Round 15
// baseline (343.053 us; speedup 1.0000x reference)
//
#include <hip/hip_runtime.h>
#include <hip/hip_fp16.h>

typedef unsigned short u16;
typedef __attribute__((ext_vector_type(8))) _Float16 f16x8;
typedef __attribute__((ext_vector_type(2))) _Float16 f16x2;
typedef __attribute__((ext_vector_type(4))) float   f32x4;

typedef const __attribute__((address_space(1))) void* gas1_t;
typedef __attribute__((address_space(3))) void*       las3_t;

#define LOG2E 1.44269504089f
#define M12   17.3123404907f   /* 12*log2(e) */

__device__ __forceinline__ void async_ld16(const void* g, void* s){
  __builtin_amdgcn_global_load_lds((gas1_t)g, (las3_t)s, 16, 0, 0);
}
__device__ __forceinline__ u16 f2h(float f){
  return __half_as_ushort(__float2half(f));   // v_cvt_f16_f32, RNE
}

// ---- merged preprocessing: cvt3 (0..1535) | mask_bits (1536..2559) |
// ----                       transcvt (2560..3583)  — all independent
__global__ void prep_kernel(const float* __restrict__ Q, const float* __restrict__ K,
                            const float* __restrict__ V, const void* __restrict__ msrc,
                            const float* __restrict__ Wq, const float* __restrict__ Wk,
                            const float* __restrict__ Wv, const float* __restrict__ Wo,
                            u16* __restrict__ Xq, u16* __restrict__ Xk, u16* __restrict__ Xv,
                            unsigned long long* __restrict__ mbits,
                            u16* __restrict__ WqT, u16* __restrict__ WkT,
                            u16* __restrict__ WvT, u16* __restrict__ WoT)
{
  __shared__ float tile[64][65];
  int bid = blockIdx.x, t = threadIdx.x;

  if(bid < 1536){                        // ---- fp32 -> fp16 convert of Q,K,V
    int zy = bid >> 9, bx = bid & 511;
    const float* s = (zy==0)? Q : (zy==1)? K : V;
    u16* d = (zy==0)? Xq : (zy==1)? Xk : Xv;
    for(int i = bx*256 + t; i < 1048576; i += 512*256){
      float4 v = ((const float4*)s)[i];
      ushort4 o; o.x=f2h(v.x); o.y=f2h(v.y); o.z=f2h(v.z); o.w=f2h(v.w);
      ((ushort4*)d)[i] = o;
    }
    return;
  }
  if(bid < 2560){                        // ---- mask: self-detect dtype + bit-pack
    __shared__ int any;
    if(t==0) any = 0;
    __syncthreads();
    {
      const unsigned int* m32 = (const unsigned int*)msrc;
      int bad = 0;
#pragma unroll
      for(int i=0;i<8;i++) if(m32[t*8+i] > 1u) bad = 1;
      if(bad) any = 1;
    }
    __syncthreads();
    int f = any;                         // 1 => byte-bool layout, 0 => int32
    int mb = bid - 1536;
    int gw = (mb*256 + t)>>6;            // row 0..4095
    int lane = t & 63;
    for(int c=0;c<32;c++){
      int idx = gw*2048 + c*64 + lane;
      unsigned v = f ? (unsigned)((const unsigned char*)msrc)[idx]
                     : ((const unsigned int*)msrc)[idx];
      unsigned long long bal = __ballot(v != 0u);
      if(lane==0) mbits[gw*32 + c] = bal;
    }
    return;
  }
  {                                      // ---- weight transpose+convert
    int wb = bid - 2560;
    int z = wb >> 8, rem = wb & 255;
    const float* W = (z==0)?Wq:(z==1)?Wk:(z==2)?Wv:Wo;
    u16* T = (z==0)?WqT:(z==1)?WkT:(z==2)?WvT:WoT;
    int k0 = (rem>>4)*64, n0v = (rem&15)*64;
    int r = t>>4, c4 = (t&15)*4;
#pragma unroll
    for(int p=0;p<4;p++){
      int rr = p*16 + r;
      float4 v = *(const float4*)&W[(size_t)(k0+rr)*1024 + n0v + c4];
      tile[rr][c4+0]=v.x; tile[rr][c4+1]=v.y; tile[rr][c4+2]=v.z; tile[rr][c4+3]=v.w;
    }
    __syncthreads();
#pragma unroll
    for(int p=0;p<4;p++){
      int rr = p*16 + r;
      ushort4 o;
      o.x = f2h(tile[c4+0][rr]); o.y = f2h(tile[c4+1][rr]);
      o.z = f2h(tile[c4+2][rr]); o.w = f2h(tile[c4+3][rr]);
      *(ushort4*)&T[(size_t)(n0v+rr)*1024 + k0 + c4] = o;
    }
  }
}

// ---------------- shared 128x128 fp16 MFMA K-loop (K=1024, B^T layout) ------
__device__ __forceinline__ void gemm_kloop(const u16* __restrict__ A, const u16* __restrict__ BT,
                                           int m0, int n0, u16* lA, u16* lB, f32x4 acc[4][4])
{
  int t = threadIdx.x, w = t>>6, l = t&63, l4 = l>>4, lm = l&15;
  int wr = w>>1, wc = w&1;
  for(int k0=0;k0<1024;k0+=32){
#pragma unroll
    for(int j=0;j<2;j++){
      int idx = j*4096 + w*1024 + l*16;
      int r = idx>>6, cb = idx&63;
      int cbs = cb ^ ((r&3)<<4);                 // source pre-swizzle (rule #21)
      async_ld16((const char*)A  + (((size_t)(m0+r))<<11) + k0*2 + cbs,
                 (char*)lA + j*4096 + w*1024);
      async_ld16((const char*)BT + (((size_t)(n0+r))<<11) + k0*2 + cbs,
                 (char*)lB + j*4096 + w*1024);
    }
    __syncthreads();
    f16x8 af[4], bfr[4];
#pragma unroll
    for(int m=0;m<4;m++){
      int ar = wr*64 + m*16 + lm;
      af[m] = *(const f16x8*)((const char*)lA + ar*64 + ((l4*16) ^ ((ar&3)<<4)));
    }
#pragma unroll
    for(int n=0;n<4;n++){
      int br = wc*64 + n*16 + lm;
      bfr[n] = *(const f16x8*)((const char*)lB + br*64 + ((l4*16) ^ ((br&3)<<4)));
    }
#pragma unroll
    for(int m=0;m<4;m++)
#pragma unroll
      for(int n=0;n<4;n++)
        acc[m][n] = __builtin_amdgcn_mfma_f32_16x16x32_f16(af[m], bfr[n], acc[m][n], 0,0,0);
    __syncthreads();
  }
}

// bijective XCD remap for a 256-block (8 n x 32 m) GEMM slice
__device__ __forceinline__ void gemm_tile_remap(int fid, int& m0, int& n0){
  int wg = (fid & 7)*32 + (fid >> 3);   // each XCD gets 4 contiguous m-tiles
  n0 = (wg & 7)*128;
  m0 = (wg >> 3)*128;
}

// ---------------- QKV projection GEMMs (z=0:Q, 1:K(*0.125), 2:V(->V^T)) -----
__global__ __launch_bounds__(256) void proj_gemm(
    const u16* __restrict__ Xq, const u16* __restrict__ Xk, const u16* __restrict__ Xv,
    const u16* __restrict__ WqT, const u16* __restrict__ WkT, const u16* __restrict__ WvT,
    const float* __restrict__ bq, const float* __restrict__ bk, const float* __restrict__ bv,
    u16* __restrict__ qb, u16* __restrict__ kbuf, u16* __restrict__ vTb)
{
  __shared__ u16 lA[4096], lB[4096];
  int z = blockIdx.y;
  const u16* A  = (z==0)?Xq :(z==1)?Xk :Xv;
  const u16* BT = (z==0)?WqT:(z==1)?WkT:WvT;
  const float* bias = (z==0)?bq:(z==1)?bk:bv;
  int m0, n0;
  gemm_tile_remap(blockIdx.x, m0, n0);
  f32x4 zf = {0.f,0.f,0.f,0.f};
  f32x4 acc[4][4];
#pragma unroll
  for(int m=0;m<4;m++)
#pragma unroll
    for(int n=0;n<4;n++) acc[m][n]=zf;
  gemm_kloop(A, BT, m0, n0, lA, lB, acc);

  int t = threadIdx.x, w = t>>6, l = t&63, l4 = l>>4, lm = l&15;
  int wr = w>>1, wc = w&1;
  float scale = (z==1)? 0.125f : 1.0f;
#pragma unroll
  for(int n=0;n<4;n++){
    int ng = n0 + wc*64 + n*16 + lm;
    float bsv = bias[ng];
#pragma unroll
    for(int m=0;m<4;m++){
      int mb = m0 + wr*64 + m*16 + l4*4;
      f32x4 c = acc[m][n];
      int bhh = ((mb>>11)<<4) + (ng>>6);
      if(z<2){
        u16* dst = (z==0)? qb : kbuf;   // [bh][l][64]
        size_t base = (((size_t)bhh)<<17) + ((size_t)(mb&2047)<<6) + (ng&63);
        dst[base      ] = f2h((c[0]+bsv)*scale);
        dst[base +  64] = f2h((c[1]+bsv)*scale);
        dst[base + 128] = f2h((c[2]+bsv)*scale);
        dst[base + 192] = f2h((c[3]+bsv)*scale);
      } else {                          // V^T: [bh][d][l]
        size_t off = (((size_t)bhh)<<17) + ((size_t)(ng&63)<<11) + (mb&2047);
        ushort4 o;
        o.x=f2h(c[0]+bsv); o.y=f2h(c[1]+bsv); o.z=f2h(c[2]+bsv); o.w=f2h(c[3]+bsv);
        *(ushort4*)(vTb + off) = o;
      }
    }
  }
}

// ---------------- fused attention, 8 waves: 4 q-groups x 2 key-halves -------
// 1024 blocks x 512 thr = 8192 waves = 100% occupancy. Wave (qg,kh) owns
// 16 q-rows x 32 keys per tile. (R13 kernel; att stores now REGULAR, not NT —
// NT acks at HBM (~900cy) pin every barrier drain; plain stores ack at L2.)
__global__ __launch_bounds__(512, 8) void attn_fused(
    const u16* __restrict__ qb, const u16* __restrict__ kb,
    const u16* __restrict__ vTb, const unsigned* __restrict__ mbits32,
    float* __restrict__ att, u16* __restrict__ ctx)
{
  __shared__ u16 ktile[4096];           // 8 KB: [key 0..63][d 0..63], XOR-swizzled
  __shared__ u16 vtile[4096];           // 8 KB: [d 0..63][key 0..63], XOR-swizzled
  __shared__ u16 pl[4][2][16][72];      // 18 KB: per-qg 2-slot P ring [q][64 keys+pad]
  __shared__ float rsum[4][2][16];      // pass-A cross-wave row sums
  int fid = blockIdx.x;
  int xcd = fid & 7, pos = fid >> 3;    // XCD-affine: bh = 4*xcd + pos/32
  int bh = (xcd<<2) + (pos>>5);
  int q0 = (pos & 31)*64;
  int b = bh>>4, h = bh&15;
  int t = threadIdx.x, w = t>>6, l = t&63, l4 = l>>4, lm = l&15;
  int qg = w>>1, kh = w&1;
  int qw = q0 + qg*16 + lm;

  const u16* qrow = qb + ((size_t)bh*2048 + qw)*64;
  f16x8 qB0 = *(const f16x8*)(qrow + l4*8);
  f16x8 qB1 = *(const f16x8*)(qrow + 32 + l4*8);

  const unsigned* mrow = mbits32 + (size_t)(b*2048 + qw)*64 + kh;  // u32 word per tile
  const char* kbase_b = (const char*)(kb  + ((size_t)bh<<17));
  const char* vbase_b = (const char*)(vTb + ((size_t)bh<<17));
  f32x4 zf = {0.f,0.f,0.f,0.f};

  int srow = t>>3, scb = (t&7)*16;      // staging: 512 threads x 16B = one 8KB tile

  // ---- pass A: row sums of exp(s-12) over this wave's key half ----
  float esum = 0.f;
  for(int kt=0;kt<32;kt++){
    async_ld16(kbase_b + (size_t)(kt*64+srow)*128 + (scb ^ ((srow&7)<<4)),
               (char*)ktile + t*16);
    __syncthreads();
    unsigned mw = mrow[kt*2];
#pragma unroll
    for(int kf=0;kf<2;kf++){
      int keyr = kh*32 + kf*16 + lm, sw = (keyr&7)<<4;
      const char* kp = (const char*)ktile + keyr*128;
      f16x8 a0 = *(const f16x8*)(kp + ((l4*16) ^ sw));
      f16x8 a1 = *(const f16x8*)(kp + ((64 + l4*16) ^ sw));
      f32x4 s = __builtin_amdgcn_mfma_f32_16x16x32_f16(a0, qB0, zf, 0,0,0);
      s = __builtin_amdgcn_mfma_f32_16x16x32_f16(a1, qB1, s, 0,0,0);
      unsigned nib = (mw >> (kf*16 + l4*4)) & 15u;
      esum += exp2f(((nib&1u)? -1e9f : s[0])*LOG2E - M12);
      esum += exp2f(((nib&2u)? -1e9f : s[1])*LOG2E - M12);
      esum += exp2f(((nib&4u)? -1e9f : s[2])*LOG2E - M12);
      esum += exp2f(((nib&8u)? -1e9f : s[3])*LOG2E - M12);
    }
    __syncthreads();
  }
  esum += __shfl_xor(esum, 16);
  esum += __shfl_xor(esum, 32);
  if(l < 16) rsum[qg][kh][l] = esum;
  __syncthreads();
  float S = rsum[qg][0][lm] + rsum[qg][1][lm];
  float lrs = -M12 - log2f(fmaxf(S, 1e-30f));

  // ---- pass B: recompute, buffer p in 2-slot ring, PV over own half ----
  f32x4 cacc[4] = {zf,zf,zf,zf};
  float* abase = att + ((size_t)bh*2048 + q0 + qg*16)*2048;

  for(int kt=0; kt<32; kt++){
    async_ld16(kbase_b + (size_t)(kt*64+srow)*128 + (scb ^ ((srow&7)<<4)),
               (char*)ktile + t*16);
    async_ld16(vbase_b + (size_t)srow*4096 + kt*128 + (scb ^ ((srow&7)<<4)),
               (char*)vtile + t*16);
    __syncthreads();                    // staging done; pl[kt&1] flush (prev use) done
    unsigned mw = mrow[kt*2];
#pragma unroll
    for(int kf=0;kf<2;kf++){
      int keyr = kh*32 + kf*16 + lm, sw = (keyr&7)<<4;
      const char* kp = (const char*)ktile + keyr*128;
      f16x8 a0 = *(const f16x8*)(kp + ((l4*16) ^ sw));
      f16x8 a1 = *(const f16x8*)(kp + ((64 + l4*16) ^ sw));
      f32x4 s = __builtin_amdgcn_mfma_f32_16x16x32_f16(a0, qB0, zf, 0,0,0);
      s = __builtin_amdgcn_mfma_f32_16x16x32_f16(a1, qB1, s, 0,0,0);
      unsigned nib = (mw >> (kf*16 + l4*4)) & 15u;
      float p0 = exp2f(((nib&1u)? -1e9f : s[0])*LOG2E + lrs);
      float p1 = exp2f(((nib&2u)? -1e9f : s[1])*LOG2E + lrs);
      float p2 = exp2f(((nib&4u)? -1e9f : s[2])*LOG2E + lrs);
      float p3 = exp2f(((nib&8u)? -1e9f : s[3])*LOG2E + lrs);
      uint2 pk;
      pk.x = __builtin_bit_cast(unsigned, __builtin_amdgcn_cvt_pkrtz(p0,p1));
      pk.y = __builtin_bit_cast(unsigned, __builtin_amdgcn_cvt_pkrtz(p2,p3));
      *(uint2*)(&pl[qg][kt&1][lm][kh*32 + kf*16 + l4*4]) = pk;   // pl[q][key]
    }
    // PV: one MFMA per d-block over this wave's 32-key half
    f16x8 pb = *(const f16x8*)(&pl[qg][kt&1][lm][kh*32 + l4*8]);
#pragma unroll
    for(int mf=0;mf<4;mf++){
      int dr = mf*16 + lm;
      f16x8 av = *(const f16x8*)((const char*)vtile + dr*128 +
                                 ((kh*64 + l4*16) ^ ((dr&7)<<4)));
      cacc[mf] = __builtin_amdgcn_mfma_f32_16x16x32_f16(av, pb, cacc[mf], 0,0,0);
    }
    __syncthreads();                    // pl[cur] complete (both kh); tiles consumed
    // flush previous tile's p (full 64 cols, both halves) to att — PLAIN stores
    if(kt > 0){
      int tp = kt-1;
      const u16* src = &pl[qg][tp&1][0][0];
#pragma unroll
      for(int s2=0;s2<2;s2++){
        int fi = kh*512 + s2*256 + l*4;
        int r = fi>>6, c = fi&63;
        uint2 ph = *(const uint2*)(src + r*72 + c);
        f16x2 h0 = __builtin_bit_cast(f16x2, ph.x);
        f16x2 h1 = __builtin_bit_cast(f16x2, ph.y);
        f32x4 o4 = { (float)h0[0], (float)h0[1], (float)h1[0], (float)h1[1] };
        *(f32x4*)(abase + (size_t)r*2048 + tp*64 + c) = o4;
      }
    }
  }
  {                                     // epilogue flush of tile 31
    const u16* src = &pl[qg][31&1][0][0];
#pragma unroll
    for(int s2=0;s2<2;s2++){
      int fi = kh*512 + s2*256 + l*4;
      int r = fi>>6, c = fi&63;
      uint2 ph = *(const uint2*)(src + r*72 + c);
      f16x2 h0 = __builtin_bit_cast(f16x2, ph.x);
      f16x2 h1 = __builtin_bit_cast(f16x2, ph.y);
      f32x4 o4 = { (float)h0[0], (float)h0[1], (float)h1[0], (float)h1[1] };
      *(f32x4*)(abase + (size_t)r*2048 + 31*64 + c) = o4;
    }
  }

  // ---- ctx: reduce the two key-half partials via (now dead) k/v tiles ----
  __syncthreads();
  float* sc = (qg<2)? (float*)ktile + qg*1024 : (float*)vtile + (qg-2)*1024;
  if(kh==1){
#pragma unroll
    for(int mf=0;mf<4;mf++) *(f32x4*)(sc + mf*256 + l*4) = cacc[mf];
  }
  __syncthreads();
  if(kh==0){
    int token = b*2048 + qw;
#pragma unroll
    for(int mf=0;mf<4;mf++){
      f32x4 o = cacc[mf] + *(const f32x4*)(sc + mf*256 + l*4);
      ushort4 u;
      u.x=f2h(o[0]); u.y=f2h(o[1]); u.z=f2h(o[2]); u.w=f2h(o[3]);
      *(ushort4*)(ctx + (size_t)token*1024 + h*64 + mf*16 + l4*4) = u;
    }
  }
}

// ---------------- output projection + bias + residual -----------------------
__global__ __launch_bounds__(256) void out_gemm(
    const u16* __restrict__ ctx, const u16* __restrict__ WoT,
    const float* __restrict__ bo, const float* __restrict__ Qres, float* __restrict__ xout)
{
  __shared__ u16 lA[4096], lB[4096];
  int m0, n0;
  gemm_tile_remap(blockIdx.x, m0, n0);
  f32x4 zf = {0.f,0.f,0.f,0.f};
  f32x4 acc[4][4];
#pragma unroll
  for(int m=0;m<4;m++)
#pragma unroll
    for(int n=0;n<4;n++) acc[m][n]=zf;
  gemm_kloop(ctx, WoT, m0, n0, lA, lB, acc);

  int t = threadIdx.x, w = t>>6, l = t&63, l4 = l>>4, lm = l&15;
  int wr = w>>1, wc = w&1;
#pragma unroll
  for(int n=0;n<4;n++){
    int ng = n0 + wc*64 + n*16 + lm;
    float bsv = bo[ng];
#pragma unroll
    for(int m=0;m<4;m++){
      int mb = m0 + wr*64 + m*16 + l4*4;
      f32x4 c = acc[m][n];
#pragma unroll
      for(int j=0;j<4;j++){
        size_t o = ((size_t)(mb+j)<<10) + ng;
        xout[o] = c[j] + bsv + Qres[o];
      }
    }
  }
}

// ---------------- LayerNorm over rows of 1024 -------------------------------
__global__ void ln_kernel(const float* __restrict__ x, const float* __restrict__ gamma,
                          const float* __restrict__ beta, float* __restrict__ y)
{
  int row = blockIdx.x, t = threadIdx.x;
  float4 v = ((const float4*)(x + (size_t)row*1024))[t];
  float s  = v.x+v.y+v.z+v.w;
  float sq = v.x*v.x + v.y*v.y + v.z*v.z + v.w*v.w;
#pragma unroll
  for(int d=1; d<64; d<<=1){ s += __shfl_xor(s, d); sq += __shfl_xor(sq, d); }
  __shared__ float red[8];
  int w = t>>6, l = t&63;
  if(l==0){ red[w] = s; red[4+w] = sq; }
  __syncthreads();
  s  = red[0]+red[1]+red[2]+red[3];
  sq = red[4]+red[5]+red[6]+red[7];
  float mu  = s * 0.0009765625f;
  float var = sq * 0.0009765625f - mu*mu;
  float rs  = rsqrtf(var + 1e-5f);
  float4 g  = ((const float4*)gamma)[t];
  float4 be = ((const float4*)beta)[t];
  float4 o;
  o.x = (v.x-mu)*rs*g.x + be.x;
  o.y = (v.y-mu)*rs*g.y + be.y;
  o.z = (v.z-mu)*rs*g.z + be.z;
  o.w = (v.w-mu)*rs*g.w + be.w;
  ((float4*)(y + (size_t)row*1024))[t] = o;
}

// ---------------- launch ----------------------------------------------------
extern "C" void kernel_launch(void* const* d_in, const int* in_sizes, int n_in,
                              void* d_out, int out_size, void* d_ws, size_t ws_size,
                              hipStream_t stream)
{
  (void)in_sizes; (void)n_in; (void)out_size; (void)ws_size;
  const float* Q    = (const float*)d_in[0];
  const float* K    = (const float*)d_in[1];
  const float* V    = (const float*)d_in[2];
  const void*  mraw = d_in[3];
  const float* Wq   = (const float*)d_in[4];
  const float* bq   = (const float*)d_in[5];
  const float* Wk   = (const float*)d_in[6];
  const float* bk   = (const float*)d_in[7];
  const float* Wv   = (const float*)d_in[8];
  const float* bv   = (const float*)d_in[9];
  const float* Wo   = (const float*)d_in[10];
  const float* bo   = (const float*)d_in[11];
  const float* gamma= (const float*)d_in[12];
  const float* beta = (const float*)d_in[13];

  char* ws = (char*)d_ws;
  const size_t MB = 1ull<<20;
  u16* WqT  = (u16*)(ws + 0*MB);
  u16* WkT  = (u16*)(ws + 2*MB);
  u16* WvT  = (u16*)(ws + 4*MB);
  u16* WoT  = (u16*)(ws + 6*MB);
  u16* Xq   = (u16*)(ws + 8*MB);
  u16* Xk   = (u16*)(ws + 16*MB);
  u16* Xv   = (u16*)(ws + 24*MB);
  u16* qb   = (u16*)(ws + 32*MB);
  u16* kbuf = (u16*)(ws + 40*MB);
  u16* vTb  = (u16*)(ws + 48*MB);
  u16* ctx  = (u16*)(ws + 56*MB);     // 56..64 MB
  float* xres = (float*)(ws + 16*MB); // reused after proj (dead Xk/Xv)

  float* yout = (float*)d_out;
  float* att  = (float*)d_out + 4194304;
  // mbits lives in the y-region of d_out (first 1 MB of 16 MB): written by
  // prep, read by attn_fused, then fully overwritten by ln_kernel at the end.
  unsigned long long* mbits = (unsigned long long*)d_out;

  prep_kernel<<<3584, 256, 0, stream>>>(Q,K,V,mraw,Wq,Wk,Wv,Wo,
                                        Xq,Xk,Xv,mbits,WqT,WkT,WvT,WoT);
  proj_gemm<<<dim3(256,3), 256, 0, stream>>>(Xq,Xk,Xv,WqT,WkT,WvT,bq,bk,bv,qb,kbuf,vTb);
  attn_fused<<<1024, 512, 0, stream>>>(qb,kbuf,vTb,(const unsigned*)mbits,att,ctx);
  out_gemm<<<256, 256, 0, stream>>>(ctx,WoT,bo,Q,xres);
  ln_kernel<<<4096, 256, 0, stream>>>(xres,gamma,beta,yout);
}

// Round 16
// 253.441 us; speedup vs baseline: 1.3536x; 1.3536x over previous
//
#include <hip/hip_runtime.h>
#include <hip/hip_fp16.h>

typedef unsigned short u16;
typedef __attribute__((ext_vector_type(8))) _Float16 f16x8;
typedef __attribute__((ext_vector_type(2))) _Float16 f16x2;
typedef __attribute__((ext_vector_type(4))) float   f32x4;

typedef const __attribute__((address_space(1))) void* gas1_t;
typedef __attribute__((address_space(3))) void*       las3_t;

#define LOG2E 1.44269504089f
#define M12   17.3123404907f   /* 12*log2(e) */

__device__ __forceinline__ void async_ld16(const void* g, void* s){
  __builtin_amdgcn_global_load_lds((gas1_t)g, (las3_t)s, 16, 0, 0);
}
__device__ __forceinline__ u16 f2h(float f){
  return __half_as_ushort(__float2half(f));   // v_cvt_f16_f32, RNE
}

// ---- merged preprocessing: cvt3 (0..1535) | mask_bits (1536..2559) |
// ----                       transcvt (2560..3583)  — all independent
__global__ void prep_kernel(const float* __restrict__ Q, const float* __restrict__ K,
                            const float* __restrict__ V, const void* __restrict__ msrc,
                            const float* __restrict__ Wq, const float* __restrict__ Wk,
                            const float* __restrict__ Wv, const float* __restrict__ Wo,
                            u16* __restrict__ Xq, u16* __restrict__ Xk, u16* __restrict__ Xv,
                            unsigned long long* __restrict__ mbits,
                            u16* __restrict__ WqT, u16* __restrict__ WkT,
                            u16* __restrict__ WvT, u16* __restrict__ WoT)
{
  __shared__ float tile[64][65];
  int bid = blockIdx.x, t = threadIdx.x;

  if(bid < 1536){                        // ---- fp32 -> fp16 convert of Q,K,V
    int zy = bid >> 9, bx = bid & 511;
    const float* s = (zy==0)? Q : (zy==1)? K : V;
    u16* d = (zy==0)? Xq : (zy==1)? Xk : Xv;
    for(int i = bx*256 + t; i < 1048576; i += 512*256){
      float4 v = ((const float4*)s)[i];
      ushort4 o; o.x=f2h(v.x); o.y=f2h(v.y); o.z=f2h(v.z); o.w=f2h(v.w);
      ((ushort4*)d)[i] = o;
    }
    return;
  }
  if(bid < 2560){                        // ---- mask: self-detect dtype + bit-pack
    __shared__ int any;
    if(t==0) any = 0;
    __syncthreads();
    {
      const unsigned int* m32 = (const unsigned int*)msrc;
      int bad = 0;
#pragma unroll
      for(int i=0;i<8;i++) if(m32[t*8+i] > 1u) bad = 1;
      if(bad) any = 1;
    }
    __syncthreads();
    int f = any;                         // 1 => byte-bool layout, 0 => int32
    int mb = bid - 1536;
    int gw = (mb*256 + t)>>6;            // row 0..4095
    int lane = t & 63;
    for(int c=0;c<32;c++){
      int idx = gw*2048 + c*64 + lane;
      unsigned v = f ? (unsigned)((const unsigned char*)msrc)[idx]
                     : ((const unsigned int*)msrc)[idx];
      unsigned long long bal = __ballot(v != 0u);
      if(lane==0) mbits[gw*32 + c] = bal;
    }
    return;
  }
  {                                      // ---- weight transpose+convert
    int wb = bid - 2560;
    int z = wb >> 8, rem = wb & 255;
    const float* W = (z==0)?Wq:(z==1)?Wk:(z==2)?Wv:Wo;
    u16* T = (z==0)?WqT:(z==1)?WkT:(z==2)?WvT:WoT;
    int k0 = (rem>>4)*64, n0v = (rem&15)*64;
    int r = t>>4, c4 = (t&15)*4;
#pragma unroll
    for(int p=0;p<4;p++){
      int rr = p*16 + r;
      float4 v = *(const float4*)&W[(size_t)(k0+rr)*1024 + n0v + c4];
      tile[rr][c4+0]=v.x; tile[rr][c4+1]=v.y; tile[rr][c4+2]=v.z; tile[rr][c4+3]=v.w;
    }
    __syncthreads();
#pragma unroll
    for(int p=0;p<4;p++){
      int rr = p*16 + r;
      ushort4 o;
      o.x = f2h(tile[c4+0][rr]); o.y = f2h(tile[c4+1][rr]);
      o.z = f2h(tile[c4+2][rr]); o.w = f2h(tile[c4+3][rr]);
      *(ushort4*)&T[(size_t)(n0v+rr)*1024 + k0 + c4] = o;
    }
  }
}

// ---------------- shared 128x128 fp16 MFMA K-loop (K=1024, B^T layout) ------
__device__ __forceinline__ void gemm_kloop(const u16* __restrict__ A, const u16* __restrict__ BT,
                                           int m0, int n0, u16* lA, u16* lB, f32x4 acc[4][4])
{
  int t = threadIdx.x, w = t>>6, l = t&63, l4 = l>>4, lm = l&15;
  int wr = w>>1, wc = w&1;
  for(int k0=0;k0<1024;k0+=32){
#pragma unroll
    for(int j=0;j<2;j++){
      int idx = j*4096 + w*1024 + l*16;
      int r = idx>>6, cb = idx&63;
      int cbs = cb ^ ((r&3)<<4);                 // source pre-swizzle (rule #21)
      async_ld16((const char*)A  + (((size_t)(m0+r))<<11) + k0*2 + cbs,
                 (char*)lA + j*4096 + w*1024);
      async_ld16((const char*)BT + (((size_t)(n0+r))<<11) + k0*2 + cbs,
                 (char*)lB + j*4096 + w*1024);
    }
    __syncthreads();
    f16x8 af[4], bfr[4];
#pragma unroll
    for(int m=0;m<4;m++){
      int ar = wr*64 + m*16 + lm;
      af[m] = *(const f16x8*)((const char*)lA + ar*64 + ((l4*16) ^ ((ar&3)<<4)));
    }
#pragma unroll
    for(int n=0;n<4;n++){
      int br = wc*64 + n*16 + lm;
      bfr[n] = *(const f16x8*)((const char*)lB + br*64 + ((l4*16) ^ ((br&3)<<4)));
    }
#pragma unroll
    for(int m=0;m<4;m++)
#pragma unroll
      for(int n=0;n<4;n++)
        acc[m][n] = __builtin_amdgcn_mfma_f32_16x16x32_f16(af[m], bfr[n], acc[m][n], 0,0,0);
    __syncthreads();
  }
}

// bijective XCD remap for a 256-block (8 n x 32 m) GEMM slice
__device__ __forceinline__ void gemm_tile_remap(int fid, int& m0, int& n0){
  int wg = (fid & 7)*32 + (fid >> 3);   // each XCD gets 4 contiguous m-tiles
  n0 = (wg & 7)*128;
  m0 = (wg >> 3)*128;
}

// ---------------- QKV projection GEMMs (z=0:Q, 1:K(*0.125), 2:V(->V^T)) -----
__global__ __launch_bounds__(256) void proj_gemm(
    const u16* __restrict__ Xq, const u16* __restrict__ Xk, const u16* __restrict__ Xv,
    const u16* __restrict__ WqT, const u16* __restrict__ WkT, const u16* __restrict__ WvT,
    const float* __restrict__ bq, const float* __restrict__ bk, const float* __restrict__ bv,
    u16* __restrict__ qb, u16* __restrict__ kbuf, u16* __restrict__ vTb)
{
  __shared__ u16 lA[4096], lB[4096];
  int z = blockIdx.y;
  const u16* A  = (z==0)?Xq :(z==1)?Xk :Xv;
  const u16* BT = (z==0)?WqT:(z==1)?WkT:WvT;
  const float* bias = (z==0)?bq:(z==1)?bk:bv;
  int m0, n0;
  gemm_tile_remap(blockIdx.x, m0, n0);
  f32x4 zf = {0.f,0.f,0.f,0.f};
  f32x4 acc[4][4];
#pragma unroll
  for(int m=0;m<4;m++)
#pragma unroll
    for(int n=0;n<4;n++) acc[m][n]=zf;
  gemm_kloop(A, BT, m0, n0, lA, lB, acc);

  int t = threadIdx.x, w = t>>6, l = t&63, l4 = l>>4, lm = l&15;
  int wr = w>>1, wc = w&1;
  float scale = (z==1)? 0.125f : 1.0f;
#pragma unroll
  for(int n=0;n<4;n++){
    int ng = n0 + wc*64 + n*16 + lm;
    float bsv = bias[ng];
#pragma unroll
    for(int m=0;m<4;m++){
      int mb = m0 + wr*64 + m*16 + l4*4;
      f32x4 c = acc[m][n];
      int bhh = ((mb>>11)<<4) + (ng>>6);
      if(z<2){
        u16* dst = (z==0)? qb : kbuf;   // [bh][l][64]
        size_t base = (((size_t)bhh)<<17) + ((size_t)(mb&2047)<<6) + (ng&63);
        dst[base      ] = f2h((c[0]+bsv)*scale);
        dst[base +  64] = f2h((c[1]+bsv)*scale);
        dst[base + 128] = f2h((c[2]+bsv)*scale);
        dst[base + 192] = f2h((c[3]+bsv)*scale);
      } else {                          // V^T: [bh][d][l]
        size_t off = (((size_t)bhh)<<17) + ((size_t)(ng&63)<<11) + (mb&2047);
        ushort4 o;
        o.x=f2h(c[0]+bsv); o.y=f2h(c[1]+bsv); o.z=f2h(c[2]+bsv); o.w=f2h(c[3]+bsv);
        *(ushort4*)(vTb + off) = o;
      }
    }
  }
}

// ---------------- fused attention, 8 waves: 4 q-groups x 2 key-halves -------
// 1024 blocks x 512 thr = 8192 waves = 100% occupancy. Wave (qg,kh) owns
// 16 q-rows x 32 keys per tile. NT stores on att are ESSENTIAL (R15: plain
// stores thrash L2 with the 537MB write stream, +88us).
__global__ __launch_bounds__(512, 8) void attn_fused(
    const u16* __restrict__ qb, const u16* __restrict__ kb,
    const u16* __restrict__ vTb, const unsigned* __restrict__ mbits32,
    float* __restrict__ att, u16* __restrict__ ctx)
{
  __shared__ u16 ktile[4096];           // 8 KB: [key 0..63][d 0..63], XOR-swizzled
  __shared__ u16 vtile[4096];           // 8 KB: [d 0..63][key 0..63], XOR-swizzled
  __shared__ u16 pl[4][2][16][72];      // 18 KB: per-qg 2-slot P ring [q][64 keys+pad]
  __shared__ float rsum[4][2][16];      // pass-A cross-wave row sums
  int fid = blockIdx.x;
  int xcd = fid & 7, pos = fid >> 3;    // XCD-affine: bh = 4*xcd + pos/32
  int bh = (xcd<<2) + (pos>>5);
  int q0 = (pos & 31)*64;
  int b = bh>>4, h = bh&15;
  int t = threadIdx.x, w = t>>6, l = t&63, l4 = l>>4, lm = l&15;
  int qg = w>>1, kh = w&1;
  int qw = q0 + qg*16 + lm;

  const u16* qrow = qb + ((size_t)bh*2048 + qw)*64;
  f16x8 qB0 = *(const f16x8*)(qrow + l4*8);
  f16x8 qB1 = *(const f16x8*)(qrow + 32 + l4*8);

  const unsigned* mrow = mbits32 + (size_t)(b*2048 + qw)*64 + kh;  // u32 word per tile
  const char* kbase_b = (const char*)(kb  + ((size_t)bh<<17));
  const char* vbase_b = (const char*)(vTb + ((size_t)bh<<17));
  f32x4 zf = {0.f,0.f,0.f,0.f};

  int srow = t>>3, scb = (t&7)*16;      // staging: 512 threads x 16B = one 8KB tile

  // ---- pass A: row sums of exp(s-12) over this wave's key half ----
  float esum = 0.f;
  for(int kt=0;kt<32;kt++){
    async_ld16(kbase_b + (size_t)(kt*64+srow)*128 + (scb ^ ((srow&7)<<4)),
               (char*)ktile + t*16);
    __syncthreads();
    unsigned mw = mrow[kt*2];
#pragma unroll
    for(int kf=0;kf<2;kf++){
      int keyr = kh*32 + kf*16 + lm, sw = (keyr&7)<<4;
      const char* kp = (const char*)ktile + keyr*128;
      f16x8 a0 = *(const f16x8*)(kp + ((l4*16) ^ sw));
      f16x8 a1 = *(const f16x8*)(kp + ((64 + l4*16) ^ sw));
      f32x4 s = __builtin_amdgcn_mfma_f32_16x16x32_f16(a0, qB0, zf, 0,0,0);
      s = __builtin_amdgcn_mfma_f32_16x16x32_f16(a1, qB1, s, 0,0,0);
      unsigned nib = (mw >> (kf*16 + l4*4)) & 15u;
      esum += exp2f(((nib&1u)? -1e9f : s[0])*LOG2E - M12);
      esum += exp2f(((nib&2u)? -1e9f : s[1])*LOG2E - M12);
      esum += exp2f(((nib&4u)? -1e9f : s[2])*LOG2E - M12);
      esum += exp2f(((nib&8u)? -1e9f : s[3])*LOG2E - M12);
    }
    __syncthreads();
  }
  esum += __shfl_xor(esum, 16);
  esum += __shfl_xor(esum, 32);
  if(l < 16) rsum[qg][kh][l] = esum;
  __syncthreads();
  float S = rsum[qg][0][lm] + rsum[qg][1][lm];
  float lrs = -M12 - log2f(fmaxf(S, 1e-30f));

  // ---- pass B: recompute, buffer p in 2-slot ring, PV over own half ----
  f32x4 cacc[4] = {zf,zf,zf,zf};
  float* abase = att + ((size_t)bh*2048 + q0 + qg*16)*2048;

  for(int kt=0; kt<32; kt++){
    async_ld16(kbase_b + (size_t)(kt*64+srow)*128 + (scb ^ ((srow&7)<<4)),
               (char*)ktile + t*16);
    async_ld16(vbase_b + (size_t)srow*4096 + kt*128 + (scb ^ ((srow&7)<<4)),
               (char*)vtile + t*16);
    __syncthreads();                    // staging done; pl[kt&1] flush (prev use) done
    unsigned mw = mrow[kt*2];
#pragma unroll
    for(int kf=0;kf<2;kf++){
      int keyr = kh*32 + kf*16 + lm, sw = (keyr&7)<<4;
      const char* kp = (const char*)ktile + keyr*128;
      f16x8 a0 = *(const f16x8*)(kp + ((l4*16) ^ sw));
      f16x8 a1 = *(const f16x8*)(kp + ((64 + l4*16) ^ sw));
      f32x4 s = __builtin_amdgcn_mfma_f32_16x16x32_f16(a0, qB0, zf, 0,0,0);
      s = __builtin_amdgcn_mfma_f32_16x16x32_f16(a1, qB1, s, 0,0,0);
      unsigned nib = (mw >> (kf*16 + l4*4)) & 15u;
      float p0 = exp2f(((nib&1u)? -1e9f : s[0])*LOG2E + lrs);
      float p1 = exp2f(((nib&2u)? -1e9f : s[1])*LOG2E + lrs);
      float p2 = exp2f(((nib&4u)? -1e9f : s[2])*LOG2E + lrs);
      float p3 = exp2f(((nib&8u)? -1e9f : s[3])*LOG2E + lrs);
      uint2 pk;
      pk.x = __builtin_bit_cast(unsigned, __builtin_amdgcn_cvt_pkrtz(p0,p1));
      pk.y = __builtin_bit_cast(unsigned, __builtin_amdgcn_cvt_pkrtz(p2,p3));
      *(uint2*)(&pl[qg][kt&1][lm][kh*32 + kf*16 + l4*4]) = pk;   // pl[q][key]
    }
    // PV: one MFMA per d-block over this wave's 32-key half
    f16x8 pb = *(const f16x8*)(&pl[qg][kt&1][lm][kh*32 + l4*8]);
#pragma unroll
    for(int mf=0;mf<4;mf++){
      int dr = mf*16 + lm;
      f16x8 av = *(const f16x8*)((const char*)vtile + dr*128 +
                                 ((kh*64 + l4*16) ^ ((dr&7)<<4)));
      cacc[mf] = __builtin_amdgcn_mfma_f32_16x16x32_f16(av, pb, cacc[mf], 0,0,0);
    }
    __syncthreads();                    // pl[cur] complete (both kh); tiles consumed
    // flush previous tile's p (full 64 cols, both halves) to att — NT stores
    if(kt > 0){
      int tp = kt-1;
      const u16* src = &pl[qg][tp&1][0][0];
#pragma unroll
      for(int s2=0;s2<2;s2++){
        int fi = kh*512 + s2*256 + l*4;
        int r = fi>>6, c = fi&63;
        uint2 ph = *(const uint2*)(src + r*72 + c);
        f16x2 h0 = __builtin_bit_cast(f16x2, ph.x);
        f16x2 h1 = __builtin_bit_cast(f16x2, ph.y);
        f32x4 o4 = { (float)h0[0], (float)h0[1], (float)h1[0], (float)h1[1] };
        __builtin_nontemporal_store(o4,
            (f32x4*)(abase + (size_t)r*2048 + tp*64 + c));
      }
    }
  }
  {                                     // epilogue flush of tile 31
    const u16* src = &pl[qg][31&1][0][0];
#pragma unroll
    for(int s2=0;s2<2;s2++){
      int fi = kh*512 + s2*256 + l*4;
      int r = fi>>6, c = fi&63;
      uint2 ph = *(const uint2*)(src + r*72 + c);
      f16x2 h0 = __builtin_bit_cast(f16x2, ph.x);
      f16x2 h1 = __builtin_bit_cast(f16x2, ph.y);
      f32x4 o4 = { (float)h0[0], (float)h0[1], (float)h1[0], (float)h1[1] };
      __builtin_nontemporal_store(o4,
          (f32x4*)(abase + (size_t)r*2048 + 31*64 + c));
    }
  }

  // ---- ctx: reduce the two key-half partials via (now dead) k/v tiles ----
  __syncthreads();
  float* sc = (qg<2)? (float*)ktile + qg*1024 : (float*)vtile + (qg-2)*1024;
  if(kh==1){
#pragma unroll
    for(int mf=0;mf<4;mf++) *(f32x4*)(sc + mf*256 + l*4) = cacc[mf];
  }
  __syncthreads();
  if(kh==0){
    int token = b*2048 + qw;
#pragma unroll
    for(int mf=0;mf<4;mf++){
      f32x4 o = cacc[mf] + *(const f32x4*)(sc + mf*256 + l*4);
      ushort4 u;
      u.x=f2h(o[0]); u.y=f2h(o[1]); u.z=f2h(o[2]); u.w=f2h(o[3]);
      *(ushort4*)(ctx + (size_t)token*1024 + h*64 + mf*16 + l4*4) = u;
    }
  }
}

// ---------------- output projection + bias + residual -----------------------
__global__ __launch_bounds__(256) void out_gemm(
    const u16* __restrict__ ctx, const u16* __restrict__ WoT,
    const float* __restrict__ bo, const float* __restrict__ Qres, float* __restrict__ xout)
{
  __shared__ u16 lA[4096], lB[4096];
  int m0, n0;
  gemm_tile_remap(blockIdx.x, m0, n0);
  f32x4 zf = {0.f,0.f,0.f,0.f};
  f32x4 acc[4][4];
#pragma unroll
  for(int m=0;m<4;m++)
#pragma unroll
    for(int n=0;n<4;n++) acc[m][n]=zf;
  gemm_kloop(ctx, WoT, m0, n0, lA, lB, acc);

  int t = threadIdx.x, w = t>>6, l = t&63, l4 = l>>4, lm = l&15;
  int wr = w>>1, wc = w&1;
#pragma unroll
  for(int n=0;n<4;n++){
    int ng = n0 + wc*64 + n*16 + lm;
    float bsv = bo[ng];
#pragma unroll
    for(int m=0;m<4;m++){
      int mb = m0 + wr*64 + m*16 + l4*4;
      f32x4 c = acc[m][n];
#pragma unroll
      for(int j=0;j<4;j++){
        size_t o = ((size_t)(mb+j)<<10) + ng;
        xout[o] = c[j] + bsv + Qres[o];
      }
    }
  }
}

// ---------------- LayerNorm over rows of 1024 -------------------------------
__global__ void ln_kernel(const float* __restrict__ x, const float* __restrict__ gamma,
                          const float* __restrict__ beta, float* __restrict__ y)
{
  int row = blockIdx.x, t = threadIdx.x;
  float4 v = ((const float4*)(x + (size_t)row*1024))[t];
  float s  = v.x+v.y+v.z+v.w;
  float sq = v.x*v.x + v.y*v.y + v.z*v.z + v.w*v.w;
#pragma unroll
  for(int d=1; d<64; d<<=1){ s += __shfl_xor(s, d); sq += __shfl_xor(sq, d); }
  __shared__ float red[8];
  int w = t>>6, l = t&63;
  if(l==0){ red[w] = s; red[4+w] = sq; }
  __syncthreads();
  s  = red[0]+red[1]+red[2]+red[3];
  sq = red[4]+red[5]+red[6]+red[7];
  float mu  = s * 0.0009765625f;
  float var = sq * 0.0009765625f - mu*mu;
  float rs  = rsqrtf(var + 1e-5f);
  float4 g  = ((const float4*)gamma)[t];
  float4 be = ((const float4*)beta)[t];
  float4 o;
  o.x = (v.x-mu)*rs*g.x + be.x;
  o.y = (v.y-mu)*rs*g.y + be.y;
  o.z = (v.z-mu)*rs*g.z + be.z;
  o.w = (v.w-mu)*rs*g.w + be.w;
  ((float4*)(y + (size_t)row*1024))[t] = o;
}

// ---------------- launch ----------------------------------------------------
extern "C" void kernel_launch(void* const* d_in, const int* in_sizes, int n_in,
                              void* d_out, int out_size, void* d_ws, size_t ws_size,
                              hipStream_t stream)
{
  (void)in_sizes; (void)n_in; (void)out_size; (void)ws_size;
  const float* Q    = (const float*)d_in[0];
  const float* K    = (const float*)d_in[1];
  const float* V    = (const float*)d_in[2];
  const void*  mraw = d_in[3];
  const float* Wq   = (const float*)d_in[4];
  const float* bq   = (const float*)d_in[5];
  const float* Wk   = (const float*)d_in[6];
  const float* bk   = (const float*)d_in[7];
  const float* Wv   = (const float*)d_in[8];
  const float* bv   = (const float*)d_in[9];
  const float* Wo   = (const float*)d_in[10];
  const float* bo   = (const float*)d_in[11];
  const float* gamma= (const float*)d_in[12];
  const float* beta = (const float*)d_in[13];

  char* ws = (char*)d_ws;
  const size_t MB = 1ull<<20;
  u16* WqT  = (u16*)(ws + 0*MB);
  u16* WkT  = (u16*)(ws + 2*MB);
  u16* WvT  = (u16*)(ws + 4*MB);
  u16* WoT  = (u16*)(ws + 6*MB);
  u16* Xq   = (u16*)(ws + 8*MB);
  u16* Xk   = (u16*)(ws + 16*MB);
  u16* Xv   = (u16*)(ws + 24*MB);
  u16* qb   = (u16*)(ws + 32*MB);
  u16* kbuf = (u16*)(ws + 40*MB);
  u16* vTb  = (u16*)(ws + 48*MB);
  u16* ctx  = (u16*)(ws + 56*MB);     // 56..64 MB
  float* xres = (float*)(ws + 16*MB); // reused after proj (dead Xk/Xv)

  float* yout = (float*)d_out;
  float* att  = (float*)d_out + 4194304;
  // mbits lives in the y-region of d_out (first 1 MB of 16 MB): written by
  // prep, read by attn_fused, then fully overwritten by ln_kernel at the end.
  unsigned long long* mbits = (unsigned long long*)d_out;

  prep_kernel<<<3584, 256, 0, stream>>>(Q,K,V,mraw,Wq,Wk,Wv,Wo,
                                        Xq,Xk,Xv,mbits,WqT,WkT,WvT,WoT);
  proj_gemm<<<dim3(256,3), 256, 0, stream>>>(Xq,Xk,Xv,WqT,WkT,WvT,bq,bk,bv,qb,kbuf,vTb);
  attn_fused<<<1024, 512, 0, stream>>>(qb,kbuf,vTb,(const unsigned*)mbits,att,ctx);
  out_gemm<<<256, 256, 0, stream>>>(ctx,WoT,bo,Q,xres);
  ln_kernel<<<4096, 256, 0, stream>>>(xres,gamma,beta,yout);
}